// Round 14
// baseline (269.993 us; speedup 1.0000x reference)
//
#include <hip/hip_runtime.h>
#include <math.h>

#define N_TOTAL   32768
#define K_ENT     4096
#define DIM       64
#define BMR       128
#define BK        128
#define CAPG      16
#define EPS       1.0f
#define BIAS      256.0f

typedef __attribute__((ext_vector_type(4))) float f32x4;
typedef __attribute__((ext_vector_type(8))) short bf16x8;
typedef __attribute__((ext_vector_type(4))) unsigned short u16x4;

// ws layout (float offsets) — total ~2.9 MB
#define WS_NCB    0            // 4096 floats: BIAS - 0.5*||w_k||^2
#define WS_WHI    4096         // 4096x64 ushort hi-plane (512 KB)
#define WS_RMX    135168       // 32768 uints: per-row biased max; ablation dummy after collect
#define WS_CNT    167936       // 32768 ints: per-row candidate count
#define WS_CAND   200704       // 32768 x CAPG ints: candidate lists (2 MB)
// out layout (fp32 element offsets)
#define OUT_ZQ    0
#define OUT_IDX   2097152
#define OUT_LOSS  2129920
#define OUT_ENC   2134016
#define OUT_EMB   2138112

#define NEG_BIG   -3.0e38f

__device__ __forceinline__ float bf2f(unsigned short u) {
  return __uint_as_float(((unsigned int)u) << 16);
}
__device__ __forceinline__ unsigned short f2bf(float f) {  // RNE
  unsigned int b = __float_as_uint(f);
  return (unsigned short)((b + 0x7fffu + ((b >> 16) & 1u)) >> 16);
}

__global__ __launch_bounds__(256) void prep_kernel(
    const float* __restrict__ w, unsigned short* __restrict__ whi,
    float* __restrict__ ncb) {
  int i = blockIdx.x * 256 + threadIdx.x;      // float4 unit, 0..65535
  float4 v = ((const float4*)w)[i];
  u16x4 h;
  h[0] = f2bf(v.x); h[1] = f2bf(v.y); h[2] = f2bf(v.z); h[3] = f2bf(v.w);
  ((u16x4*)whi)[i] = h;
  float s = fmaf(v.x, v.x, fmaf(v.y, v.y, fmaf(v.z, v.z, v.w * v.w)));
  s += __shfl_xor(s, 1); s += __shfl_xor(s, 2);
  s += __shfl_xor(s, 4); s += __shfl_xor(s, 8);
  if ((threadIdx.x & 15) == 0) ncb[i >> 4] = BIAS - 0.5f * s;
}

// Phase 1: per-row biased max. Block = 128 rows x quarter of K (grid 1024,
// 12 waves/CU at (256,3)). Swapped operands (A=w, B=z). 2-deep named
// prefetch, NO LDS/barriers. atomicMax on float-as-uint.
__global__ __launch_bounds__(256, 3) void maxes_kernel(
    const float* __restrict__ z, const unsigned short* __restrict__ whi,
    const float* __restrict__ ncb, unsigned int* __restrict__ rmx) {
  const int tid = threadIdx.x;
  const int n0  = (blockIdx.x >> 2) * BMR;
  const int kq  = blockIdx.x & 3;
  const int st  = blockIdx.x & 7;
  const int wv  = tid >> 6;
  const int ln  = tid & 63;
  const int g   = ln >> 4;
  const int lm  = ln & 15;
  const int estripe = wv * 32;

  bf16x8 bz[8][2];
  #pragma unroll
  for (int rt = 0; rt < 8; ++rt) {
    const float* zr = z + (size_t)(n0 + rt * 16 + lm) * DIM;
    #pragma unroll
    for (int s = 0; s < 2; ++s) {
      float4 f0 = *(const float4*)(zr + s * 32 + g * 8);
      float4 f1 = *(const float4*)(zr + s * 32 + g * 8 + 4);
      float ff[8] = {f0.x, f0.y, f0.z, f0.w, f1.x, f1.y, f1.z, f1.w};
      bf16x8 h;
      #pragma unroll
      for (int i = 0; i < 8; ++i) h[i] = (short)f2bf(ff[i]);
      bz[rt][s] = h;
    }
  }

  float m[8];
  #pragma unroll
  for (int i = 0; i < 8; ++i) m[i] = NEG_BIG;

  bf16x8 awA[2][2], awB[2][2];
  float4 ncA[2], ncB[2];

  auto chunkbase = [&](int i) { return (kq * 8 + ((i + st) & 7)) * BK; };
  auto loadW = [&](int kcb, bf16x8 (&aw)[2][2], float4 (&nc)[2]) {
    #pragma unroll
    for (int et = 0; et < 2; ++et) {
      const int ebase = kcb + estripe + et * 16;
      nc[et] = *(const float4*)(ncb + ebase + g * 4);
      const unsigned short* wr = whi + (size_t)(ebase + lm) * DIM + g * 8;
      aw[et][0] = *(const bf16x8*)(wr);
      aw[et][1] = *(const bf16x8*)(wr + 32);
    }
  };
  auto comp = [&](const bf16x8 (&aw)[2][2], const float4 (&nc)[2]) {
    f32x4 acc[2][8];
    #pragma unroll
    for (int et = 0; et < 2; ++et)
      #pragma unroll
      for (int rt = 0; rt < 8; ++rt)
        acc[et][rt] = (f32x4){nc[et].x, nc[et].y, nc[et].z, nc[et].w};
    #pragma unroll
    for (int et = 0; et < 2; ++et)
      #pragma unroll
      for (int s = 0; s < 2; ++s)
        #pragma unroll
        for (int rt = 0; rt < 8; ++rt)
          acc[et][rt] = __builtin_amdgcn_mfma_f32_16x16x32_bf16(
              aw[et][s], bz[rt][s], acc[et][rt], 0, 0, 0);
    #pragma unroll
    for (int rt = 0; rt < 8; ++rt) {
      float cm = fmaxf(
          fmaxf(fmaxf(acc[0][rt][0], acc[0][rt][1]),
                fmaxf(acc[0][rt][2], acc[0][rt][3])),
          fmaxf(fmaxf(acc[1][rt][0], acc[1][rt][1]),
                fmaxf(acc[1][rt][2], acc[1][rt][3])));
      m[rt] = fmaxf(m[rt], cm);
    }
  };

  loadW(chunkbase(0), awA, ncA);
  #pragma unroll 1
  for (int i = 0; i < 8; i += 2) {
    loadW(chunkbase(i + 1), awB, ncB);
    comp(awA, ncA);
    if (i + 2 < 8) loadW(chunkbase(i + 2), awA, ncA);
    comp(awB, ncB);
  }

  #pragma unroll
  for (int rt = 0; rt < 8; ++rt) {
    m[rt] = fmaxf(m[rt], __shfl_xor(m[rt], 16));
    m[rt] = fmaxf(m[rt], __shfl_xor(m[rt], 32));
  }
  if (ln < 16) {
    #pragma unroll
    for (int rt = 0; rt < 8; ++rt)
      atomicMax(&rmx[n0 + rt * 16 + ln], __float_as_uint(m[rt]));
  }
}

// Phase 2: identical sweep, collect entries >= rowmax - EPS.
__global__ __launch_bounds__(256, 3) void collect_kernel(
    const float* __restrict__ z, const unsigned short* __restrict__ whi,
    const float* __restrict__ ncb, const unsigned int* __restrict__ rmx,
    int* __restrict__ cnt, int* __restrict__ cand) {
  const int tid = threadIdx.x;
  const int n0  = (blockIdx.x >> 2) * BMR;
  const int kq  = blockIdx.x & 3;
  const int st  = blockIdx.x & 7;
  const int wv  = tid >> 6;
  const int ln  = tid & 63;
  const int g   = ln >> 4;
  const int lm  = ln & 15;
  const int estripe = wv * 32;

  bf16x8 bz[8][2];
  #pragma unroll
  for (int rt = 0; rt < 8; ++rt) {
    const float* zr = z + (size_t)(n0 + rt * 16 + lm) * DIM;
    #pragma unroll
    for (int s = 0; s < 2; ++s) {
      float4 f0 = *(const float4*)(zr + s * 32 + g * 8);
      float4 f1 = *(const float4*)(zr + s * 32 + g * 8 + 4);
      float ff[8] = {f0.x, f0.y, f0.z, f0.w, f1.x, f1.y, f1.z, f1.w};
      bf16x8 h;
      #pragma unroll
      for (int i = 0; i < 8; ++i) h[i] = (short)f2bf(ff[i]);
      bz[rt][s] = h;
    }
  }

  float thr[8];
  #pragma unroll
  for (int rt = 0; rt < 8; ++rt)
    thr[rt] = __uint_as_float(rmx[n0 + rt * 16 + lm]) - EPS;

  bf16x8 awA[2][2], awB[2][2];
  float4 ncA[2], ncB[2];

  auto chunkbase = [&](int i) { return (kq * 8 + ((i + st) & 7)) * BK; };
  auto loadW = [&](int kcb, bf16x8 (&aw)[2][2], float4 (&nc)[2]) {
    #pragma unroll
    for (int et = 0; et < 2; ++et) {
      const int ebase = kcb + estripe + et * 16;
      nc[et] = *(const float4*)(ncb + ebase + g * 4);
      const unsigned short* wr = whi + (size_t)(ebase + lm) * DIM + g * 8;
      aw[et][0] = *(const bf16x8*)(wr);
      aw[et][1] = *(const bf16x8*)(wr + 32);
    }
  };
  auto comp = [&](int kcb, const bf16x8 (&aw)[2][2], const float4 (&nc)[2]) {
    f32x4 acc[2][8];
    #pragma unroll
    for (int et = 0; et < 2; ++et)
      #pragma unroll
      for (int rt = 0; rt < 8; ++rt)
        acc[et][rt] = (f32x4){nc[et].x, nc[et].y, nc[et].z, nc[et].w};
    #pragma unroll
    for (int et = 0; et < 2; ++et)
      #pragma unroll
      for (int s = 0; s < 2; ++s)
        #pragma unroll
        for (int rt = 0; rt < 8; ++rt)
          acc[et][rt] = __builtin_amdgcn_mfma_f32_16x16x32_bf16(
              aw[et][s], bz[rt][s], acc[et][rt], 0, 0, 0);
    #pragma unroll
    for (int rt = 0; rt < 8; ++rt) {
      float hm = fmaxf(
          fmaxf(fmaxf(acc[0][rt][0], acc[0][rt][1]),
                fmaxf(acc[0][rt][2], acc[0][rt][3])),
          fmaxf(fmaxf(acc[1][rt][0], acc[1][rt][1]),
                fmaxf(acc[1][rt][2], acc[1][rt][3])));
      if (__builtin_expect(hm >= thr[rt], 0)) {   // rare
        const int rown = n0 + rt * 16 + lm;
        #pragma unroll
        for (int et = 0; et < 2; ++et)
          #pragma unroll
          for (int j = 0; j < 4; ++j) {
            if (acc[et][rt][j] >= thr[rt]) {
              int e = kcb + estripe + et * 16 + g * 4 + j;
              int p = atomicAdd(&cnt[rown], 1);
              if (p < CAPG) cand[rown * CAPG + p] = e;
            }
          }
      }
    }
  };

  loadW(chunkbase(0), awA, ncA);
  #pragma unroll 1
  for (int i = 0; i < 8; i += 2) {
    loadW(chunkbase(i + 1), awB, ncB);
    comp(chunkbase(i), awA, ncA);
    if (i + 2 < 8) loadW(chunkbase(i + 2), awA, ncA);
    comp(chunkbase(i + 1), awB, ncB);
  }
}

// ===== ABLATION A: pure load pipeline (r13 collect's exact load loop, =====
// ===== MFMA replaced by xor sink). grid 512, (256,2), 16 chunks.       =====
__global__ __launch_bounds__(256, 2) void abl_load_kernel(
    const unsigned short* __restrict__ whi, const float* __restrict__ ncb,
    unsigned int* __restrict__ dummy) {
  const int tid = threadIdx.x;
  const int khalf = blockIdx.x & 1;
  const int st  = blockIdx.x & 15;
  const int wv  = tid >> 6;
  const int ln  = tid & 63;
  const int g   = ln >> 4;
  const int lm  = ln & 15;
  const int estripe = wv * 32;

  bf16x8 awA[2][2], awB[2][2];
  float4 ncA[2], ncB[2];
  unsigned int red = 0;

  auto chunkbase = [&](int i) { return (khalf * 16 + ((i + st) & 15)) * BK; };
  auto loadW = [&](int kcb, bf16x8 (&aw)[2][2], float4 (&nc)[2]) {
    #pragma unroll
    for (int et = 0; et < 2; ++et) {
      const int ebase = kcb + estripe + et * 16;
      nc[et] = *(const float4*)(ncb + ebase + g * 4);
      const unsigned short* wr = whi + (size_t)(ebase + lm) * DIM + g * 8;
      aw[et][0] = *(const bf16x8*)(wr);
      aw[et][1] = *(const bf16x8*)(wr + 32);
    }
  };
  auto consume = [&](const bf16x8 (&aw)[2][2], const float4 (&nc)[2]) {
    #pragma unroll
    for (int et = 0; et < 2; ++et) {
      #pragma unroll
      for (int s = 0; s < 2; ++s) {
        float4 v = *(const float4*)&aw[et][s];
        red ^= __float_as_uint(v.x) ^ __float_as_uint(v.y) ^
               __float_as_uint(v.z) ^ __float_as_uint(v.w);
      }
      red ^= __float_as_uint(nc[et].x) ^ __float_as_uint(nc[et].w);
    }
  };

  loadW(chunkbase(0), awA, ncA);
  #pragma unroll 1
  for (int i = 0; i < 16; i += 2) {
    loadW(chunkbase(i + 1), awB, ncB);
    consume(awA, ncA);
    if (i + 2 < 16) loadW(chunkbase(i + 2), awA, ncA);
    consume(awB, ncB);
  }
  if (ln == 0) dummy[blockIdx.x * 4 + wv] = red;
}

// ===== ABLATION B: pure MFMA pipeline (loads hoisted; 16 iters x 32    =====
// ===== accumulating MFMAs on fixed operands). grid 512, (256,2).       =====
__global__ __launch_bounds__(256, 2) void abl_mfma_kernel(
    const float* __restrict__ z, const unsigned short* __restrict__ whi,
    const float* __restrict__ ncb, unsigned int* __restrict__ dummy) {
  const int tid = threadIdx.x;
  const int n0  = (blockIdx.x >> 1) * BMR;
  const int khalf = blockIdx.x & 1;
  const int wv  = tid >> 6;
  const int ln  = tid & 63;
  const int g   = ln >> 4;
  const int lm  = ln & 15;
  const int estripe = wv * 32;

  bf16x8 bz[8][2];
  #pragma unroll
  for (int rt = 0; rt < 8; ++rt) {
    const float* zr = z + (size_t)(n0 + rt * 16 + lm) * DIM;
    #pragma unroll
    for (int s = 0; s < 2; ++s) {
      float4 f0 = *(const float4*)(zr + s * 32 + g * 8);
      float4 f1 = *(const float4*)(zr + s * 32 + g * 8 + 4);
      float ff[8] = {f0.x, f0.y, f0.z, f0.w, f1.x, f1.y, f1.z, f1.w};
      bf16x8 h;
      #pragma unroll
      for (int i = 0; i < 8; ++i) h[i] = (short)f2bf(ff[i]);
      bz[rt][s] = h;
    }
  }

  bf16x8 aw[2][2];
  float4 nc[2];
  {
    const int kcb = khalf * 16 * BK;
    #pragma unroll
    for (int et = 0; et < 2; ++et) {
      const int ebase = kcb + estripe + et * 16;
      nc[et] = *(const float4*)(ncb + ebase + g * 4);
      const unsigned short* wr = whi + (size_t)(ebase + lm) * DIM + g * 8;
      aw[et][0] = *(const bf16x8*)(wr);
      aw[et][1] = *(const bf16x8*)(wr + 32);
    }
  }

  f32x4 acc[2][8];
  #pragma unroll
  for (int et = 0; et < 2; ++et)
    #pragma unroll
    for (int rt = 0; rt < 8; ++rt)
      acc[et][rt] = (f32x4){nc[et].x, nc[et].y, nc[et].z, nc[et].w};

  #pragma unroll 1
  for (int it = 0; it < 16; ++it) {
    #pragma unroll
    for (int et = 0; et < 2; ++et)
      #pragma unroll
      for (int s = 0; s < 2; ++s)
        #pragma unroll
        for (int rt = 0; rt < 8; ++rt)
          acc[et][rt] = __builtin_amdgcn_mfma_f32_16x16x32_bf16(
              aw[et][s], bz[rt][s], acc[et][rt], 0, 0, 0);
  }

  float red = NEG_BIG;
  #pragma unroll
  for (int et = 0; et < 2; ++et)
    #pragma unroll
    for (int rt = 0; rt < 8; ++rt)
      red = fmaxf(red, fmaxf(fmaxf(acc[et][rt][0], acc[et][rt][1]),
                             fmaxf(acc[et][rt][2], acc[et][rt][3])));
  if (ln == 0) dummy[2048 + blockIdx.x * 4 + wv] = __float_as_uint(red);
}

// Exact fp64 rescore (lane-per-candidate) + gather/loss/scatter.
__global__ __launch_bounds__(512) void rescore_gather_kernel(
    const float* __restrict__ z, const float* __restrict__ w,
    const int* __restrict__ cnt, const int* __restrict__ cand,
    float* __restrict__ out_idx, float* __restrict__ out_zq,
    float* __restrict__ out_loss, float* __restrict__ enc,
    float* __restrict__ emb) {
  const int bs = blockIdx.x;
  const int tid = threadIdx.x;
  const int h = tid >> 6, d = tid & 63;
  const int n = bs * 8 + h;

  int nn = cnt[n];
  double bl = -1.0e300;
  int wl = 0x7fffffff;
  if (nn <= CAPG) {
    if (d < nn) {                       // lane d rescores candidate d
      int c = cand[n * CAPG + d];
      double td = 0.0, ud = 0.0;
      #pragma unroll 8
      for (int d2 = 0; d2 < DIM; ++d2) {
        double wv = (double)w[(size_t)c * DIM + d2];
        double zv = (double)z[(size_t)n * DIM + d2];
        td = fma(zv, wv, td);
        ud = fma(wv, wv, ud);
      }
      bl = 2.0 * td - ud;
      wl = c;
    }
  } else {                              // overflow: full exact scan (P~0)
    for (int t = 0; t < 64; ++t) {
      int c = t * 64 + d;
      double td = 0.0, ud = 0.0;
      for (int d2 = 0; d2 < DIM; ++d2) {
        double wv = (double)w[(size_t)c * DIM + d2];
        double zv = (double)z[(size_t)n * DIM + d2];
        td = fma(zv, wv, td);
        ud = fma(wv, wv, ud);
      }
      double sd = 2.0 * td - ud;
      if (sd > bl || (sd == bl && c < wl)) { bl = sd; wl = c; }
    }
  }
  #pragma unroll
  for (int mk = 1; mk <= 32; mk <<= 1) {
    double os = __shfl_xor(bl, mk);
    int   oi = __shfl_xor(wl, mk);
    if (os > bl || (os == bl && oi < wl)) { bl = os; wl = oi; }
  }
  int k = wl;
  k = (k < 0) ? 0 : ((k > K_ENT - 1) ? (K_ENT - 1) : k);  // safety clamp
  if (d == 0) out_idx[n] = (float)k;

  const float zf = z[(size_t)n * DIM + d];
  float wvf = w[(size_t)k * DIM + d];
  float stv = zf + (wvf - zf);              // straight-through, ref fp order
  out_zq[(size_t)n * DIM + d] = stv;
  float diff = zf - wvf;
  float s = diff * diff;
  #pragma unroll
  for (int mm = 32; mm >= 1; mm >>= 1) s += __shfl_down(s, mm, 64);
  __shared__ float red[8];
  if ((tid & 63) == 0) red[tid >> 6] = s;
  __syncthreads();
  if (tid == 0) {
    float t = 0.f;
    #pragma unroll
    for (int i = 0; i < 8; ++i) t += red[i];
    out_loss[bs] = t * (1.0f / 512.0f);
  }
  atomicAdd(&emb[(size_t)k * DIM + d], zf);
  if (d == 0) atomicAdd(&enc[k], 1.0f);
}

extern "C" void kernel_launch(void* const* d_in, const int* in_sizes, int n_in,
                              void* d_out, int out_size, void* d_ws, size_t ws_size,
                              hipStream_t stream) {
  const float* z = (const float*)d_in[0];
  const float* w = (const float*)d_in[1];
  float* ws  = (float*)d_ws;
  float* ncb = ws + WS_NCB;
  unsigned short* whi = (unsigned short*)(ws + WS_WHI);
  unsigned int* rmx = (unsigned int*)(ws + WS_RMX);
  int* cnt  = (int*)(ws + WS_CNT);
  int* cand = (int*)(ws + WS_CAND);
  float* out = (float*)d_out;

  hipMemsetAsync(out + OUT_ENC, 0, (size_t)(4096 + 262144) * sizeof(float),
                 stream);
  hipMemsetAsync(rmx, 0, (size_t)(2 * N_TOTAL) * sizeof(int), stream);

  prep_kernel<<<(K_ENT * DIM / 4) / 256, 256, 0, stream>>>(w, whi, ncb);
  maxes_kernel<<<(N_TOTAL / BMR) * 4, 256, 0, stream>>>(z, whi, ncb, rmx);
  collect_kernel<<<(N_TOTAL / BMR) * 4, 256, 0, stream>>>(z, whi, ncb, rmx,
                                                          cnt, cand);
  // ---- diagnostics (write only to rmx scratch, which is dead after collect)
  abl_load_kernel<<<512, 256, 0, stream>>>(whi, ncb, rmx);
  abl_mfma_kernel<<<512, 256, 0, stream>>>(z, whi, ncb, rmx);
  // ----
  rescore_gather_kernel<<<N_TOTAL / 8, 512, 0, stream>>>(
      z, w, cnt, cand, out + OUT_IDX, out + OUT_ZQ, out + OUT_LOSS,
      out + OUT_ENC, out + OUT_EMB);
}

// Round 15
// 180.413 us; speedup vs baseline: 1.4965x; 1.4965x over previous
//
#include <hip/hip_runtime.h>
#include <math.h>

#define N_TOTAL   32768
#define K_ENT     4096
#define DIM       64
#define BMR       128
#define BK        128
#define CAPG      16
#define EPS       1.0f
#define BIAS      256.0f

typedef __attribute__((ext_vector_type(4))) float f32x4;
typedef __attribute__((ext_vector_type(8))) short bf16x8;
typedef __attribute__((ext_vector_type(4))) unsigned short u16x4;

// ws layout (float offsets) — total ~2.9 MB
#define WS_NCB    0            // 4096 floats: BIAS - 0.5*||w_k||^2
#define WS_WHI    4096         // 4096x64 ushort hi-plane (512 KB)
#define WS_RMX    135168       // 32768 uints: rowmax; ablation dummy after collect
#define WS_CNT    167936       // 32768 ints: per-row candidate count
#define WS_CAND   200704       // 32768 x CAPG ints: candidate lists (2 MB)
// out layout (fp32 element offsets)
#define OUT_ZQ    0
#define OUT_IDX   2097152
#define OUT_LOSS  2129920
#define OUT_ENC   2134016
#define OUT_EMB   2138112

#define NEG_BIG   -3.0e38f

// inline-asm 16B load + counted waits (T4): loads invisible to the
// compiler's waitcnt tracking -> no conservative drain before MFMA; we
// place the exact waits ourselves, fenced per rule #18.
#define GLOAD(dst, ptr) \
  asm volatile("global_load_dwordx4 %0, %1, off" : "=&v"(dst) : "v"(ptr))
#define VMWAIT(n) asm volatile("s_waitcnt vmcnt(" #n ")")
#define SB0() __builtin_amdgcn_sched_barrier(0)

__device__ __forceinline__ float bf2f(unsigned short u) {
  return __uint_as_float(((unsigned int)u) << 16);
}
__device__ __forceinline__ unsigned short f2bf(float f) {  // RNE
  unsigned int b = __float_as_uint(f);
  return (unsigned short)((b + 0x7fffu + ((b >> 16) & 1u)) >> 16);
}

__global__ __launch_bounds__(256) void prep_kernel(
    const float* __restrict__ w, unsigned short* __restrict__ whi,
    float* __restrict__ ncb) {
  int i = blockIdx.x * 256 + threadIdx.x;      // float4 unit, 0..65535
  float4 v = ((const float4*)w)[i];
  u16x4 h;
  h[0] = f2bf(v.x); h[1] = f2bf(v.y); h[2] = f2bf(v.z); h[3] = f2bf(v.w);
  ((u16x4*)whi)[i] = h;
  float s = fmaf(v.x, v.x, fmaf(v.y, v.y, fmaf(v.z, v.z, v.w * v.w)));
  s += __shfl_xor(s, 1); s += __shfl_xor(s, 2);
  s += __shfl_xor(s, 4); s += __shfl_xor(s, 8);
  if ((threadIdx.x & 15) == 0) ncb[i >> 4] = BIAS - 0.5f * s;
}

// Phase 1: per-row biased max. r13 config: (256,2), BMR=128, K-split 2,
// grid 512, NO LDS/barriers — but with asm loads + counted vmcnt(6).
__global__ __launch_bounds__(256, 2) void maxes_kernel(
    const float* __restrict__ z, const unsigned short* __restrict__ whi,
    const float* __restrict__ ncb, unsigned int* __restrict__ rmx) {
  const int tid = threadIdx.x;
  const int n0  = (blockIdx.x >> 1) * BMR;
  const int khalf = blockIdx.x & 1;
  const int st  = blockIdx.x & 15;
  const int wv  = tid >> 6;
  const int ln  = tid & 63;
  const int g   = ln >> 4;
  const int lm  = ln & 15;
  const int estripe = wv * 32;

  bf16x8 bz[8][2];
  #pragma unroll
  for (int rt = 0; rt < 8; ++rt) {
    const float* zr = z + (size_t)(n0 + rt * 16 + lm) * DIM;
    #pragma unroll
    for (int s = 0; s < 2; ++s) {
      float4 f0 = *(const float4*)(zr + s * 32 + g * 8);
      float4 f1 = *(const float4*)(zr + s * 32 + g * 8 + 4);
      float ff[8] = {f0.x, f0.y, f0.z, f0.w, f1.x, f1.y, f1.z, f1.w};
      bf16x8 h;
      #pragma unroll
      for (int i = 0; i < 8; ++i) h[i] = (short)f2bf(ff[i]);
      bz[rt][s] = h;
    }
  }

  float m[8];
  #pragma unroll
  for (int i = 0; i < 8; ++i) m[i] = NEG_BIG;

  bf16x8 awA[2][2], awB[2][2];
  f32x4  ncA[2], ncB[2];

  auto chunkbase = [&](int i) { return (khalf * 16 + ((i + st) & 15)) * BK; };
  // 6 asm loads per call (4x aw + 2x nc), in fixed issue order
  auto loadW = [&](int kcb, bf16x8 (&aw)[2][2], f32x4 (&nc)[2]) {
    #pragma unroll
    for (int et = 0; et < 2; ++et) {
      const int ebase = kcb + estripe + et * 16;
      const unsigned short* wr = whi + (size_t)(ebase + lm) * DIM + g * 8;
      GLOAD(aw[et][0], wr);
      GLOAD(aw[et][1], wr + 32);
      GLOAD(nc[et], ncb + ebase + g * 4);
    }
  };
  auto comp = [&](const bf16x8 (&aw)[2][2], const f32x4 (&nc)[2]) {
    f32x4 acc[2][8];
    #pragma unroll
    for (int et = 0; et < 2; ++et)
      #pragma unroll
      for (int rt = 0; rt < 8; ++rt)
        acc[et][rt] = (f32x4){nc[et][0], nc[et][1], nc[et][2], nc[et][3]};
    #pragma unroll
    for (int et = 0; et < 2; ++et)
      #pragma unroll
      for (int s = 0; s < 2; ++s)
        #pragma unroll
        for (int rt = 0; rt < 8; ++rt)
          acc[et][rt] = __builtin_amdgcn_mfma_f32_16x16x32_bf16(
              aw[et][s], bz[rt][s], acc[et][rt], 0, 0, 0);
    #pragma unroll
    for (int rt = 0; rt < 8; ++rt) {
      float cm = fmaxf(
          fmaxf(fmaxf(acc[0][rt][0], acc[0][rt][1]),
                fmaxf(acc[0][rt][2], acc[0][rt][3])),
          fmaxf(fmaxf(acc[1][rt][0], acc[1][rt][1]),
                fmaxf(acc[1][rt][2], acc[1][rt][3])));
      m[rt] = fmaxf(m[rt], cm);
    }
  };

  loadW(chunkbase(0), awA, ncA);              // 6 outstanding
  #pragma unroll 1
  for (int i = 0; i < 16; i += 2) {
    loadW(chunkbase(i + 1), awB, ncB);        // 12 outstanding
    VMWAIT(6); SB0();                         // A's 6 complete
    comp(awA, ncA);
    if (i + 2 < 16) {
      loadW(chunkbase(i + 2), awA, ncA);      // 12 outstanding
      VMWAIT(6);                              // B's 6 complete
    } else {
      VMWAIT(0);
    }
    SB0();
    comp(awB, ncB);
  }

  #pragma unroll
  for (int rt = 0; rt < 8; ++rt) {
    m[rt] = fmaxf(m[rt], __shfl_xor(m[rt], 16));
    m[rt] = fmaxf(m[rt], __shfl_xor(m[rt], 32));
  }
  if (ln < 16) {
    #pragma unroll
    for (int rt = 0; rt < 8; ++rt)
      atomicMax(&rmx[n0 + rt * 16 + ln], __float_as_uint(m[rt]));
  }
}

// Phase 2: identical sweep (bit-identical scores), collect >= rowmax-EPS.
__global__ __launch_bounds__(256, 2) void collect_kernel(
    const float* __restrict__ z, const unsigned short* __restrict__ whi,
    const float* __restrict__ ncb, const unsigned int* __restrict__ rmx,
    int* __restrict__ cnt, int* __restrict__ cand) {
  const int tid = threadIdx.x;
  const int n0  = (blockIdx.x >> 1) * BMR;
  const int khalf = blockIdx.x & 1;
  const int st  = blockIdx.x & 15;
  const int wv  = tid >> 6;
  const int ln  = tid & 63;
  const int g   = ln >> 4;
  const int lm  = ln & 15;
  const int estripe = wv * 32;

  bf16x8 bz[8][2];
  #pragma unroll
  for (int rt = 0; rt < 8; ++rt) {
    const float* zr = z + (size_t)(n0 + rt * 16 + lm) * DIM;
    #pragma unroll
    for (int s = 0; s < 2; ++s) {
      float4 f0 = *(const float4*)(zr + s * 32 + g * 8);
      float4 f1 = *(const float4*)(zr + s * 32 + g * 8 + 4);
      float ff[8] = {f0.x, f0.y, f0.z, f0.w, f1.x, f1.y, f1.z, f1.w};
      bf16x8 h;
      #pragma unroll
      for (int i = 0; i < 8; ++i) h[i] = (short)f2bf(ff[i]);
      bz[rt][s] = h;
    }
  }

  float thr[8];
  #pragma unroll
  for (int rt = 0; rt < 8; ++rt)
    thr[rt] = __uint_as_float(rmx[n0 + rt * 16 + lm]) - EPS;

  bf16x8 awA[2][2], awB[2][2];
  f32x4  ncA[2], ncB[2];

  auto chunkbase = [&](int i) { return (khalf * 16 + ((i + st) & 15)) * BK; };
  auto loadW = [&](int kcb, bf16x8 (&aw)[2][2], f32x4 (&nc)[2]) {
    #pragma unroll
    for (int et = 0; et < 2; ++et) {
      const int ebase = kcb + estripe + et * 16;
      const unsigned short* wr = whi + (size_t)(ebase + lm) * DIM + g * 8;
      GLOAD(aw[et][0], wr);
      GLOAD(aw[et][1], wr + 32);
      GLOAD(nc[et], ncb + ebase + g * 4);
    }
  };
  auto comp = [&](int kcb, const bf16x8 (&aw)[2][2], const f32x4 (&nc)[2]) {
    f32x4 acc[2][8];
    #pragma unroll
    for (int et = 0; et < 2; ++et)
      #pragma unroll
      for (int rt = 0; rt < 8; ++rt)
        acc[et][rt] = (f32x4){nc[et][0], nc[et][1], nc[et][2], nc[et][3]};
    #pragma unroll
    for (int et = 0; et < 2; ++et)
      #pragma unroll
      for (int s = 0; s < 2; ++s)
        #pragma unroll
        for (int rt = 0; rt < 8; ++rt)
          acc[et][rt] = __builtin_amdgcn_mfma_f32_16x16x32_bf16(
              aw[et][s], bz[rt][s], acc[et][rt], 0, 0, 0);
    #pragma unroll
    for (int rt = 0; rt < 8; ++rt) {
      float hm = fmaxf(
          fmaxf(fmaxf(acc[0][rt][0], acc[0][rt][1]),
                fmaxf(acc[0][rt][2], acc[0][rt][3])),
          fmaxf(fmaxf(acc[1][rt][0], acc[1][rt][1]),
                fmaxf(acc[1][rt][2], acc[1][rt][3])));
      if (__builtin_expect(hm >= thr[rt], 0)) {   // rare
        const int rown = n0 + rt * 16 + lm;
        #pragma unroll
        for (int et = 0; et < 2; ++et)
          #pragma unroll
          for (int j = 0; j < 4; ++j) {
            if (acc[et][rt][j] >= thr[rt]) {
              int e = kcb + estripe + et * 16 + g * 4 + j;
              int p = atomicAdd(&cnt[rown], 1);
              if (p < CAPG) cand[rown * CAPG + p] = e;
            }
          }
      }
    }
  };

  loadW(chunkbase(0), awA, ncA);
  #pragma unroll 1
  for (int i = 0; i < 16; i += 2) {
    loadW(chunkbase(i + 1), awB, ncB);
    VMWAIT(6); SB0();
    comp(chunkbase(i), awA, ncA);
    if (i + 2 < 16) {
      loadW(chunkbase(i + 2), awA, ncA);
      VMWAIT(6);
    } else {
      VMWAIT(0);
    }
    SB0();
    comp(chunkbase(i + 1), awB, ncB);
  }
}

// ===== ABLATION A: pure load pipeline, compiler-scheduled, 32 chunks  =====
// ===== (2 sweeps' worth). Read per-sweep cost = dur/2.                =====
__global__ __launch_bounds__(256, 2) void abl_load_kernel(
    const unsigned short* __restrict__ whi, const float* __restrict__ ncb,
    unsigned int* __restrict__ dummy) {
  const int tid = threadIdx.x;
  const int khalf = blockIdx.x & 1;
  const int st  = blockIdx.x & 15;
  const int wv  = tid >> 6;
  const int ln  = tid & 63;
  const int g   = ln >> 4;
  const int lm  = ln & 15;
  const int estripe = wv * 32;

  bf16x8 awA[2][2], awB[2][2];
  float4 ncA[2], ncB[2];
  unsigned int red = 0;

  auto chunkbase = [&](int i) { return (khalf * 16 + ((i + st) & 15)) * BK; };
  auto loadW = [&](int kcb, bf16x8 (&aw)[2][2], float4 (&nc)[2]) {
    #pragma unroll
    for (int et = 0; et < 2; ++et) {
      const int ebase = kcb + estripe + et * 16;
      nc[et] = *(const float4*)(ncb + ebase + g * 4);
      const unsigned short* wr = whi + (size_t)(ebase + lm) * DIM + g * 8;
      aw[et][0] = *(const bf16x8*)(wr);
      aw[et][1] = *(const bf16x8*)(wr + 32);
    }
  };
  auto consume = [&](const bf16x8 (&aw)[2][2], const float4 (&nc)[2]) {
    #pragma unroll
    for (int et = 0; et < 2; ++et) {
      #pragma unroll
      for (int s = 0; s < 2; ++s) {
        float4 v = *(const float4*)&aw[et][s];
        red ^= __float_as_uint(v.x) ^ __float_as_uint(v.y) ^
               __float_as_uint(v.z) ^ __float_as_uint(v.w);
      }
      red ^= __float_as_uint(nc[et].x) ^ __float_as_uint(nc[et].w);
    }
  };

  loadW(chunkbase(0), awA, ncA);
  #pragma unroll 1
  for (int i = 0; i < 32; i += 2) {
    loadW(chunkbase(i + 1), awB, ncB);
    consume(awA, ncA);
    if (i + 2 < 32) loadW(chunkbase(i + 2), awA, ncA);
    consume(awB, ncB);
  }
  if (ln == 0) dummy[blockIdx.x * 4 + wv] = red;
}

// ===== ABLATION B: pure MFMA pipeline, 32 iters x 32 MFMAs (2 sweeps). =====
__global__ __launch_bounds__(256, 2) void abl_mfma_kernel(
    const float* __restrict__ z, const unsigned short* __restrict__ whi,
    const float* __restrict__ ncb, unsigned int* __restrict__ dummy) {
  const int tid = threadIdx.x;
  const int n0  = (blockIdx.x >> 1) * BMR;
  const int khalf = blockIdx.x & 1;
  const int wv  = tid >> 6;
  const int ln  = tid & 63;
  const int g   = ln >> 4;
  const int lm  = ln & 15;
  const int estripe = wv * 32;

  bf16x8 bz[8][2];
  #pragma unroll
  for (int rt = 0; rt < 8; ++rt) {
    const float* zr = z + (size_t)(n0 + rt * 16 + lm) * DIM;
    #pragma unroll
    for (int s = 0; s < 2; ++s) {
      float4 f0 = *(const float4*)(zr + s * 32 + g * 8);
      float4 f1 = *(const float4*)(zr + s * 32 + g * 8 + 4);
      float ff[8] = {f0.x, f0.y, f0.z, f0.w, f1.x, f1.y, f1.z, f1.w};
      bf16x8 h;
      #pragma unroll
      for (int i = 0; i < 8; ++i) h[i] = (short)f2bf(ff[i]);
      bz[rt][s] = h;
    }
  }

  bf16x8 aw[2][2];
  float4 nc[2];
  {
    const int kcb = khalf * 16 * BK;
    #pragma unroll
    for (int et = 0; et < 2; ++et) {
      const int ebase = kcb + estripe + et * 16;
      nc[et] = *(const float4*)(ncb + ebase + g * 4);
      const unsigned short* wr = whi + (size_t)(ebase + lm) * DIM + g * 8;
      aw[et][0] = *(const bf16x8*)(wr);
      aw[et][1] = *(const bf16x8*)(wr + 32);
    }
  }

  f32x4 acc[2][8];
  #pragma unroll
  for (int et = 0; et < 2; ++et)
    #pragma unroll
    for (int rt = 0; rt < 8; ++rt)
      acc[et][rt] = (f32x4){nc[et].x, nc[et].y, nc[et].z, nc[et].w};

  #pragma unroll 1
  for (int it = 0; it < 32; ++it) {
    #pragma unroll
    for (int et = 0; et < 2; ++et)
      #pragma unroll
      for (int s = 0; s < 2; ++s)
        #pragma unroll
        for (int rt = 0; rt < 8; ++rt)
          acc[et][rt] = __builtin_amdgcn_mfma_f32_16x16x32_bf16(
              aw[et][s], bz[rt][s], acc[et][rt], 0, 0, 0);
  }

  float red = NEG_BIG;
  #pragma unroll
  for (int et = 0; et < 2; ++et)
    #pragma unroll
    for (int rt = 0; rt < 8; ++rt)
      red = fmaxf(red, fmaxf(fmaxf(acc[et][rt][0], acc[et][rt][1]),
                             fmaxf(acc[et][rt][2], acc[et][rt][3])));
  if (ln == 0) dummy[2048 + blockIdx.x * 4 + wv] = __float_as_uint(red);
}

// Exact fp64 rescore (lane-per-candidate) + gather/loss/scatter.
__global__ __launch_bounds__(512) void rescore_gather_kernel(
    const float* __restrict__ z, const float* __restrict__ w,
    const int* __restrict__ cnt, const int* __restrict__ cand,
    float* __restrict__ out_idx, float* __restrict__ out_zq,
    float* __restrict__ out_loss, float* __restrict__ enc,
    float* __restrict__ emb) {
  const int bs = blockIdx.x;
  const int tid = threadIdx.x;
  const int h = tid >> 6, d = tid & 63;
  const int n = bs * 8 + h;

  int nn = cnt[n];
  double bl = -1.0e300;
  int wl = 0x7fffffff;
  if (nn <= CAPG) {
    if (d < nn) {                       // lane d rescores candidate d
      int c = cand[n * CAPG + d];
      double td = 0.0, ud = 0.0;
      #pragma unroll 8
      for (int d2 = 0; d2 < DIM; ++d2) {
        double wv = (double)w[(size_t)c * DIM + d2];
        double zv = (double)z[(size_t)n * DIM + d2];
        td = fma(zv, wv, td);
        ud = fma(wv, wv, ud);
      }
      bl = 2.0 * td - ud;
      wl = c;
    }
  } else {                              // overflow: full exact scan (P~0)
    for (int t = 0; t < 64; ++t) {
      int c = t * 64 + d;
      double td = 0.0, ud = 0.0;
      for (int d2 = 0; d2 < DIM; ++d2) {
        double wv = (double)w[(size_t)c * DIM + d2];
        double zv = (double)z[(size_t)n * DIM + d2];
        td = fma(zv, wv, td);
        ud = fma(wv, wv, ud);
      }
      double sd = 2.0 * td - ud;
      if (sd > bl || (sd == bl && c < wl)) { bl = sd; wl = c; }
    }
  }
  #pragma unroll
  for (int mk = 1; mk <= 32; mk <<= 1) {
    double os = __shfl_xor(bl, mk);
    int   oi = __shfl_xor(wl, mk);
    if (os > bl || (os == bl && oi < wl)) { bl = os; wl = oi; }
  }
  int k = wl;
  k = (k < 0) ? 0 : ((k > K_ENT - 1) ? (K_ENT - 1) : k);  // safety clamp
  if (d == 0) out_idx[n] = (float)k;

  const float zf = z[(size_t)n * DIM + d];
  float wvf = w[(size_t)k * DIM + d];
  float stv = zf + (wvf - zf);              // straight-through, ref fp order
  out_zq[(size_t)n * DIM + d] = stv;
  float diff = zf - wvf;
  float s = diff * diff;
  #pragma unroll
  for (int mm = 32; mm >= 1; mm >>= 1) s += __shfl_down(s, mm, 64);
  __shared__ float red[8];
  if ((tid & 63) == 0) red[tid >> 6] = s;
  __syncthreads();
  if (tid == 0) {
    float t = 0.f;
    #pragma unroll
    for (int i = 0; i < 8; ++i) t += red[i];
    out_loss[bs] = t * (1.0f / 512.0f);
  }
  atomicAdd(&emb[(size_t)k * DIM + d], zf);
  if (d == 0) atomicAdd(&enc[k], 1.0f);
}

extern "C" void kernel_launch(void* const* d_in, const int* in_sizes, int n_in,
                              void* d_out, int out_size, void* d_ws, size_t ws_size,
                              hipStream_t stream) {
  const float* z = (const float*)d_in[0];
  const float* w = (const float*)d_in[1];
  float* ws  = (float*)d_ws;
  float* ncb = ws + WS_NCB;
  unsigned short* whi = (unsigned short*)(ws + WS_WHI);
  unsigned int* rmx = (unsigned int*)(ws + WS_RMX);
  int* cnt  = (int*)(ws + WS_CNT);
  int* cand = (int*)(ws + WS_CAND);
  float* out = (float*)d_out;

  hipMemsetAsync(out + OUT_ENC, 0, (size_t)(4096 + 262144) * sizeof(float),
                 stream);
  hipMemsetAsync(rmx, 0, (size_t)(2 * N_TOTAL) * sizeof(int), stream);

  prep_kernel<<<(K_ENT * DIM / 4) / 256, 256, 0, stream>>>(w, whi, ncb);
  maxes_kernel<<<(N_TOTAL / BMR) * 2, 256, 0, stream>>>(z, whi, ncb, rmx);
  collect_kernel<<<(N_TOTAL / BMR) * 2, 256, 0, stream>>>(z, whi, ncb, rmx,
                                                          cnt, cand);
  // ---- diagnostics (rmx is dead after collect; real outputs untouched) ----
  abl_load_kernel<<<512, 256, 0, stream>>>(whi, ncb, rmx);
  abl_mfma_kernel<<<512, 256, 0, stream>>>(z, whi, ncb, rmx);
  // ----
  rescore_gather_kernel<<<N_TOTAL / 8, 512, 0, stream>>>(
      z, w, cnt, cand, out + OUT_IDX, out + OUT_ZQ, out + OUT_LOSS,
      out + OUT_ENC, out + OUT_EMB);
}

// Round 16
// 132.172 us; speedup vs baseline: 2.0427x; 1.3650x over previous
//
#include <hip/hip_runtime.h>
#include <math.h>

#define N_TOTAL   32768
#define K_ENT     4096
#define DIM       64
#define BMR       128
#define BK        128
#define CAPG      16
#define EPS       1.0f
#define BIAS      256.0f

typedef __attribute__((ext_vector_type(4))) float f32x4;
typedef __attribute__((ext_vector_type(8))) short bf16x8;
typedef __attribute__((ext_vector_type(4))) unsigned short u16x4;

// ws layout (float offsets) — total ~2.9 MB
#define WS_NCB    0            // 4096 floats: BIAS - 0.5*||w_k||^2
#define WS_WHI    4096         // packed bf16 hi-plane (512 KB)
#define WS_RMX    135168       // 32768 uints: per-row biased max (as uint)
#define WS_CNT    167936       // 32768 ints: per-row candidate count
#define WS_CAND   200704       // 32768 x CAPG ints: candidate lists (2 MB)
// out layout (fp32 element offsets)
#define OUT_ZQ    0
#define OUT_IDX   2097152
#define OUT_LOSS  2129920
#define OUT_ENC   2134016
#define OUT_EMB   2138112

#define NEG_BIG   -3.0e38f

// inline-asm 16B load + counted waits (kept from r15 — neutral but gives a
// deterministic schedule), fenced per rule #18.
#define GLOAD(dst, ptr) \
  asm volatile("global_load_dwordx4 %0, %1, off" : "=&v"(dst) : "v"(ptr))
#define VMWAIT(n) asm volatile("s_waitcnt vmcnt(" #n ")")
#define SB0() __builtin_amdgcn_sched_barrier(0)

__device__ __forceinline__ float bf2f(unsigned short u) {
  return __uint_as_float(((unsigned int)u) << 16);
}
__device__ __forceinline__ unsigned short f2bf(float f) {  // RNE
  unsigned int b = __float_as_uint(f);
  return (unsigned short)((b + 0x7fffu + ((b >> 16) & 1u)) >> 16);
}

// prep: ncb = BIAS - 0.5||w||^2, and whi packed FRAGMENT-CONTIGUOUS:
// fragment (e16, s) = the exact 1KB a wave loads for a 16-entry block's
// k-half s: lane ln holds whi_orig[(e16*16 + (ln&15))*64 + s*32 + (ln>>4)*8
// .. +8]. Packed at ushort index ((e16*2+s)*64 + ln)*8. Wave loads become
// fully contiguous (base + ln*8), chunk footprint sequential.
__global__ __launch_bounds__(256) void prep_kernel(
    const float* __restrict__ w, unsigned short* __restrict__ whiP,
    float* __restrict__ ncb) {
  int i = blockIdx.x * 256 + threadIdx.x;      // float4 unit, 0..65535
  float4 v = ((const float4*)w)[i];
  u16x4 h;
  h[0] = f2bf(v.x); h[1] = f2bf(v.y); h[2] = f2bf(v.z); h[3] = f2bf(v.w);
  const int e   = i >> 4;          // entry
  const int us  = (i & 15) * 4;    // ushort offset within row, 0..60
  const int s   = us >> 5;
  const int w32 = us & 31;
  const int g   = w32 >> 3;
  const int rem = w32 & 7;         // 0 or 4
  const int ln  = g * 16 + (e & 15);
  const size_t pidx = ((size_t)((e >> 4) * 2 + s) * 64 + ln) * 8 + rem;
  *(u16x4*)(whiP + pidx) = h;
  float sq = fmaf(v.x, v.x, fmaf(v.y, v.y, fmaf(v.z, v.z, v.w * v.w)));
  sq += __shfl_xor(sq, 1); sq += __shfl_xor(sq, 2);
  sq += __shfl_xor(sq, 4); sq += __shfl_xor(sq, 8);
  if ((threadIdx.x & 15) == 0) ncb[i >> 4] = BIAS - 0.5f * sq;
}

// Phase 1: per-row biased max. K-split 4 (grid 1024, 4 blocks/CU; VGPR ~120
// -> 4 waves/SIMD -> 16 waves/CU). Swapped operands (A=w, B=z); packed
// contiguous fragment loads; 2-deep named prefetch; counted vmcnt; NO LDS.
__global__ __launch_bounds__(256, 2) void maxes_kernel(
    const float* __restrict__ z, const unsigned short* __restrict__ whiP,
    const float* __restrict__ ncb, unsigned int* __restrict__ rmx) {
  const int tid = threadIdx.x;
  const int n0  = (blockIdx.x >> 2) * BMR;
  const int kq  = blockIdx.x & 3;
  const int st  = blockIdx.x & 7;
  const int wv  = tid >> 6;
  const int ln  = tid & 63;
  const int g   = ln >> 4;
  const int lm  = ln & 15;
  const int estripe = wv * 32;

  bf16x8 bz[8][2];
  #pragma unroll
  for (int rt = 0; rt < 8; ++rt) {
    const float* zr = z + (size_t)(n0 + rt * 16 + lm) * DIM;
    #pragma unroll
    for (int s = 0; s < 2; ++s) {
      float4 f0 = *(const float4*)(zr + s * 32 + g * 8);
      float4 f1 = *(const float4*)(zr + s * 32 + g * 8 + 4);
      float ff[8] = {f0.x, f0.y, f0.z, f0.w, f1.x, f1.y, f1.z, f1.w};
      bf16x8 h;
      #pragma unroll
      for (int i = 0; i < 8; ++i) h[i] = (short)f2bf(ff[i]);
      bz[rt][s] = h;
    }
  }

  float m[8];
  #pragma unroll
  for (int i = 0; i < 8; ++i) m[i] = NEG_BIG;

  bf16x8 awA[2][2], awB[2][2];
  f32x4  ncA[2], ncB[2];

  auto chunkbase = [&](int i) { return (kq * 8 + ((i + st) & 7)) * BK; };
  // 6 asm loads per call; aw fragments are contiguous 1KB wave-loads
  auto loadW = [&](int kcb, bf16x8 (&aw)[2][2], f32x4 (&nc)[2]) {
    #pragma unroll
    for (int et = 0; et < 2; ++et) {
      const int ebase = kcb + estripe + et * 16;
      const unsigned short* wrp =
          whiP + ((size_t)(ebase >> 4) * 2) * 512 + (size_t)ln * 8;
      GLOAD(aw[et][0], wrp);
      GLOAD(aw[et][1], wrp + 512);
      GLOAD(nc[et], ncb + ebase + g * 4);
    }
  };
  auto comp = [&](const bf16x8 (&aw)[2][2], const f32x4 (&nc)[2]) {
    f32x4 acc[2][8];
    #pragma unroll
    for (int et = 0; et < 2; ++et)
      #pragma unroll
      for (int rt = 0; rt < 8; ++rt)
        acc[et][rt] = (f32x4){nc[et][0], nc[et][1], nc[et][2], nc[et][3]};
    #pragma unroll
    for (int et = 0; et < 2; ++et)
      #pragma unroll
      for (int s = 0; s < 2; ++s)
        #pragma unroll
        for (int rt = 0; rt < 8; ++rt)
          acc[et][rt] = __builtin_amdgcn_mfma_f32_16x16x32_bf16(
              aw[et][s], bz[rt][s], acc[et][rt], 0, 0, 0);
    #pragma unroll
    for (int rt = 0; rt < 8; ++rt) {
      float cm = fmaxf(
          fmaxf(fmaxf(acc[0][rt][0], acc[0][rt][1]),
                fmaxf(acc[0][rt][2], acc[0][rt][3])),
          fmaxf(fmaxf(acc[1][rt][0], acc[1][rt][1]),
                fmaxf(acc[1][rt][2], acc[1][rt][3])));
      m[rt] = fmaxf(m[rt], cm);
    }
  };

  loadW(chunkbase(0), awA, ncA);              // 6 outstanding
  #pragma unroll 1
  for (int i = 0; i < 8; i += 2) {
    loadW(chunkbase(i + 1), awB, ncB);        // 12 outstanding
    VMWAIT(6); SB0();
    comp(awA, ncA);
    if (i + 2 < 8) {
      loadW(chunkbase(i + 2), awA, ncA);
      VMWAIT(6);
    } else {
      VMWAIT(0);
    }
    SB0();
    comp(awB, ncB);
  }

  #pragma unroll
  for (int rt = 0; rt < 8; ++rt) {
    m[rt] = fmaxf(m[rt], __shfl_xor(m[rt], 16));
    m[rt] = fmaxf(m[rt], __shfl_xor(m[rt], 32));
  }
  if (ln < 16) {
    #pragma unroll
    for (int rt = 0; rt < 8; ++rt)
      atomicMax(&rmx[n0 + rt * 16 + ln], __float_as_uint(m[rt]));
  }
}

// Phase 2: identical sweep (bit-identical scores), collect >= rowmax-EPS.
__global__ __launch_bounds__(256, 2) void collect_kernel(
    const float* __restrict__ z, const unsigned short* __restrict__ whiP,
    const float* __restrict__ ncb, const unsigned int* __restrict__ rmx,
    int* __restrict__ cnt, int* __restrict__ cand) {
  const int tid = threadIdx.x;
  const int n0  = (blockIdx.x >> 2) * BMR;
  const int kq  = blockIdx.x & 3;
  const int st  = blockIdx.x & 7;
  const int wv  = tid >> 6;
  const int ln  = tid & 63;
  const int g   = ln >> 4;
  const int lm  = ln & 15;
  const int estripe = wv * 32;

  bf16x8 bz[8][2];
  #pragma unroll
  for (int rt = 0; rt < 8; ++rt) {
    const float* zr = z + (size_t)(n0 + rt * 16 + lm) * DIM;
    #pragma unroll
    for (int s = 0; s < 2; ++s) {
      float4 f0 = *(const float4*)(zr + s * 32 + g * 8);
      float4 f1 = *(const float4*)(zr + s * 32 + g * 8 + 4);
      float ff[8] = {f0.x, f0.y, f0.z, f0.w, f1.x, f1.y, f1.z, f1.w};
      bf16x8 h;
      #pragma unroll
      for (int i = 0; i < 8; ++i) h[i] = (short)f2bf(ff[i]);
      bz[rt][s] = h;
    }
  }

  float thr[8];
  #pragma unroll
  for (int rt = 0; rt < 8; ++rt)
    thr[rt] = __uint_as_float(rmx[n0 + rt * 16 + lm]) - EPS;

  bf16x8 awA[2][2], awB[2][2];
  f32x4  ncA[2], ncB[2];

  auto chunkbase = [&](int i) { return (kq * 8 + ((i + st) & 7)) * BK; };
  auto loadW = [&](int kcb, bf16x8 (&aw)[2][2], f32x4 (&nc)[2]) {
    #pragma unroll
    for (int et = 0; et < 2; ++et) {
      const int ebase = kcb + estripe + et * 16;
      const unsigned short* wrp =
          whiP + ((size_t)(ebase >> 4) * 2) * 512 + (size_t)ln * 8;
      GLOAD(aw[et][0], wrp);
      GLOAD(aw[et][1], wrp + 512);
      GLOAD(nc[et], ncb + ebase + g * 4);
    }
  };
  auto comp = [&](int kcb, const bf16x8 (&aw)[2][2], const f32x4 (&nc)[2]) {
    f32x4 acc[2][8];
    #pragma unroll
    for (int et = 0; et < 2; ++et)
      #pragma unroll
      for (int rt = 0; rt < 8; ++rt)
        acc[et][rt] = (f32x4){nc[et][0], nc[et][1], nc[et][2], nc[et][3]};
    #pragma unroll
    for (int et = 0; et < 2; ++et)
      #pragma unroll
      for (int s = 0; s < 2; ++s)
        #pragma unroll
        for (int rt = 0; rt < 8; ++rt)
          acc[et][rt] = __builtin_amdgcn_mfma_f32_16x16x32_bf16(
              aw[et][s], bz[rt][s], acc[et][rt], 0, 0, 0);
    #pragma unroll
    for (int rt = 0; rt < 8; ++rt) {
      float hm = fmaxf(
          fmaxf(fmaxf(acc[0][rt][0], acc[0][rt][1]),
                fmaxf(acc[0][rt][2], acc[0][rt][3])),
          fmaxf(fmaxf(acc[1][rt][0], acc[1][rt][1]),
                fmaxf(acc[1][rt][2], acc[1][rt][3])));
      if (__builtin_expect(hm >= thr[rt], 0)) {   // rare
        const int rown = n0 + rt * 16 + lm;
        #pragma unroll
        for (int et = 0; et < 2; ++et)
          #pragma unroll
          for (int j = 0; j < 4; ++j) {
            if (acc[et][rt][j] >= thr[rt]) {
              int e = kcb + estripe + et * 16 + g * 4 + j;
              int p = atomicAdd(&cnt[rown], 1);
              if (p < CAPG) cand[rown * CAPG + p] = e;
            }
          }
      }
    }
  };

  loadW(chunkbase(0), awA, ncA);
  #pragma unroll 1
  for (int i = 0; i < 8; i += 2) {
    loadW(chunkbase(i + 1), awB, ncB);
    VMWAIT(6); SB0();
    comp(chunkbase(i), awA, ncA);
    if (i + 2 < 8) {
      loadW(chunkbase(i + 2), awA, ncA);
      VMWAIT(6);
    } else {
      VMWAIT(0);
    }
    SB0();
    comp(chunkbase(i + 1), awB, ncB);
  }
}

// Exact fp64 rescore (lane-per-candidate) + gather/loss/scatter.
__global__ __launch_bounds__(512) void rescore_gather_kernel(
    const float* __restrict__ z, const float* __restrict__ w,
    const int* __restrict__ cnt, const int* __restrict__ cand,
    float* __restrict__ out_idx, float* __restrict__ out_zq,
    float* __restrict__ out_loss, float* __restrict__ enc,
    float* __restrict__ emb) {
  const int bs = blockIdx.x;
  const int tid = threadIdx.x;
  const int h = tid >> 6, d = tid & 63;
  const int n = bs * 8 + h;

  int nn = cnt[n];
  double bl = -1.0e300;
  int wl = 0x7fffffff;
  if (nn <= CAPG) {
    if (d < nn) {                       // lane d rescores candidate d
      int c = cand[n * CAPG + d];
      double td = 0.0, ud = 0.0;
      #pragma unroll 8
      for (int d2 = 0; d2 < DIM; ++d2) {
        double wv = (double)w[(size_t)c * DIM + d2];
        double zv = (double)z[(size_t)n * DIM + d2];
        td = fma(zv, wv, td);
        ud = fma(wv, wv, ud);
      }
      bl = 2.0 * td - ud;
      wl = c;
    }
  } else {                              // overflow: full exact scan (P~0)
    for (int t = 0; t < 64; ++t) {
      int c = t * 64 + d;
      double td = 0.0, ud = 0.0;
      for (int d2 = 0; d2 < DIM; ++d2) {
        double wv = (double)w[(size_t)c * DIM + d2];
        double zv = (double)z[(size_t)n * DIM + d2];
        td = fma(zv, wv, td);
        ud = fma(wv, wv, ud);
      }
      double sd = 2.0 * td - ud;
      if (sd > bl || (sd == bl && c < wl)) { bl = sd; wl = c; }
    }
  }
  #pragma unroll
  for (int mk = 1; mk <= 32; mk <<= 1) {
    double os = __shfl_xor(bl, mk);
    int   oi = __shfl_xor(wl, mk);
    if (os > bl || (os == bl && oi < wl)) { bl = os; wl = oi; }
  }
  int k = wl;
  k = (k < 0) ? 0 : ((k > K_ENT - 1) ? (K_ENT - 1) : k);  // safety clamp
  if (d == 0) out_idx[n] = (float)k;

  const float zf = z[(size_t)n * DIM + d];
  float wvf = w[(size_t)k * DIM + d];
  float stv = zf + (wvf - zf);              // straight-through, ref fp order
  out_zq[(size_t)n * DIM + d] = stv;
  float diff = zf - wvf;
  float s = diff * diff;
  #pragma unroll
  for (int mm = 32; mm >= 1; mm >>= 1) s += __shfl_down(s, mm, 64);
  __shared__ float red[8];
  if ((tid & 63) == 0) red[tid >> 6] = s;
  __syncthreads();
  if (tid == 0) {
    float t = 0.f;
    #pragma unroll
    for (int i = 0; i < 8; ++i) t += red[i];
    out_loss[bs] = t * (1.0f / 512.0f);
  }
  atomicAdd(&emb[(size_t)k * DIM + d], zf);
  if (d == 0) atomicAdd(&enc[k], 1.0f);
}

extern "C" void kernel_launch(void* const* d_in, const int* in_sizes, int n_in,
                              void* d_out, int out_size, void* d_ws, size_t ws_size,
                              hipStream_t stream) {
  const float* z = (const float*)d_in[0];
  const float* w = (const float*)d_in[1];
  float* ws  = (float*)d_ws;
  float* ncb = ws + WS_NCB;
  unsigned short* whiP = (unsigned short*)(ws + WS_WHI);
  unsigned int* rmx = (unsigned int*)(ws + WS_RMX);
  int* cnt  = (int*)(ws + WS_CNT);
  int* cand = (int*)(ws + WS_CAND);
  float* out = (float*)d_out;

  hipMemsetAsync(out + OUT_ENC, 0, (size_t)(4096 + 262144) * sizeof(float),
                 stream);
  hipMemsetAsync(rmx, 0, (size_t)(2 * N_TOTAL) * sizeof(int), stream);

  prep_kernel<<<(K_ENT * DIM / 4) / 256, 256, 0, stream>>>(w, whiP, ncb);
  maxes_kernel<<<(N_TOTAL / BMR) * 4, 256, 0, stream>>>(z, whiP, ncb, rmx);
  collect_kernel<<<(N_TOTAL / BMR) * 4, 256, 0, stream>>>(z, whiP, ncb, rmx,
                                                          cnt, cand);
  rescore_gather_kernel<<<N_TOTAL / 8, 512, 0, stream>>>(
      z, w, cnt, cand, out + OUT_IDX, out + OUT_ZQ, out + OUT_LOSS,
      out + OUT_ENC, out + OUT_EMB);
}